// Round 1
// baseline (334.188 us; speedup 1.0000x reference)
//
#include <hip/hip_runtime.h>

// BFP quantize: x shape (N=64, C=256, H=56, W=56) fp32, tile=8 along C.
// Per tile: e = floor(log2(max(|x|, 2^-23))); step = 2^(e-6);
// q = clip(rne(x/step), -127, 127) * step.
//
// Layout: channel stride = HW = 3136 floats = 784 float4. Each thread owns
// one channel-tile x 4 consecutive spatial positions: 8 strided float4 loads
// (each coalesced across the wave) + 8 float4 stores.

#define HW4   784        // 56*56/4 float4 per channel plane
#define CTILES 32        // 256 channels / tile 8
#define NBATCH 64

__global__ __launch_bounds__(256)
void bfp_quant_kernel(const float* __restrict__ in, float* __restrict__ out) {
    const int idx = blockIdx.x * 256 + threadIdx.x;   // [0, CTILES*HW4) within one n
    const int n   = blockIdx.y;
    const int ct  = idx / HW4;                        // channel tile
    const int s4  = idx - ct * HW4;                   // float4 spatial slot

    const size_t base = (size_t)n * (256 * HW4) + (size_t)ct * (8 * HW4) + (size_t)s4;
    const float4* __restrict__ in4  = (const float4*)in;
    float4* __restrict__ out4       = (float4*)out;

    float x[8][4];
    #pragma unroll
    for (int j = 0; j < 8; ++j) {
        float4 t = in4[base + (size_t)j * HW4];
        x[j][0] = t.x; x[j][1] = t.y; x[j][2] = t.z; x[j][3] = t.w;
    }

    #pragma unroll
    for (int k = 0; k < 4; ++k) {
        // max |x| over the 8-channel tile, clamped below by eps = 2^-23 (a
        // normal float, so exponent-bit extraction == floor(log2) exactly).
        float ma = 0x1p-23f;
        #pragma unroll
        for (int j = 0; j < 8; ++j) ma = fmaxf(ma, fabsf(x[j][k]));

        const int e = (int)((__float_as_uint(ma) >> 23) & 0xFF) - 127;   // floor(log2(ma))
        const float step = __uint_as_float((unsigned)(e + 121) << 23);   // 2^(e-6)
        const float inv  = __uint_as_float((unsigned)(133 - e) << 23);   // 2^(6-e), exact

        #pragma unroll
        for (int j = 0; j < 8; ++j) {
            float q = rintf(x[j][k] * inv);            // round half to even
            q = fminf(fmaxf(q, -127.0f), 127.0f);
            x[j][k] = q * step;                        // exact pow2 scale
        }
    }

    #pragma unroll
    for (int j = 0; j < 8; ++j) {
        float4 t;
        t.x = x[j][0]; t.y = x[j][1]; t.z = x[j][2]; t.w = x[j][3];
        out4[base + (size_t)j * HW4] = t;
    }
}

extern "C" void kernel_launch(void* const* d_in, const int* in_sizes, int n_in,
                              void* d_out, int out_size, void* d_ws, size_t ws_size,
                              hipStream_t stream) {
    const float* in = (const float*)d_in[0];
    float* out = (float*)d_out;
    // per-n work: 32 channel-tiles * 784 float4 = 25088 threads = 98 blocks of 256
    dim3 grid(98, NBATCH);
    bfp_quant_kernel<<<grid, 256, 0, stream>>>(in, out);
}

// Round 2
// 323.221 us; speedup vs baseline: 1.0339x; 1.0339x over previous
//
#include <hip/hip_runtime.h>

// BFP quantize: x shape (N=64, C=256, H=56, W=56) fp32, tile=8 along C.
// Per tile: e = floor(log2(max(|x|, 2^-23))); step = 2^(e-6);
// q = clip(rne(x/step), -127, 127) * step.
//
// Layout: channel stride = HW = 3136 floats = 784 float4. Each thread owns
// one channel-tile x 4 consecutive spatial positions: 8 strided float4 loads
// (each coalesced across the wave: 64 lanes x 16 B = 1 KiB contiguous) +
// 8 float4 stores. Streaming, zero reuse -> nontemporal hints to skip
// L2/L3 allocation.

#define HW4   784        // 56*56/4 float4 per channel plane
#define NBATCH 64

typedef float v4f __attribute__((ext_vector_type(4)));

__global__ __launch_bounds__(256)
void bfp_quant_kernel(const v4f* __restrict__ in4, v4f* __restrict__ out4) {
    const int idx = blockIdx.x * 256 + threadIdx.x;   // [0, 32*HW4) within one n
    const int n   = blockIdx.y;
    const int ct  = idx / HW4;                        // channel tile (magic-mul div)
    const int s4  = idx - ct * HW4;                   // float4 spatial slot

    const size_t base = (size_t)n * (256 * HW4) + (size_t)ct * (8 * HW4) + (size_t)s4;

    v4f x[8];
    #pragma unroll
    for (int j = 0; j < 8; ++j)
        x[j] = __builtin_nontemporal_load(&in4[base + (size_t)j * HW4]);

    #pragma unroll
    for (int k = 0; k < 4; ++k) {
        // max |x| over the 8-channel tile, clamped below by eps = 2^-23 (a
        // normal float -> exponent-bit extraction == floor(log2) exactly).
        float ma = 0x1p-23f;
        #pragma unroll
        for (int j = 0; j < 8; ++j) ma = fmaxf(ma, fabsf(x[j][k]));

        const int e = (int)((__float_as_uint(ma) >> 23) & 0xFF) - 127;   // floor(log2(ma))
        const float step = __uint_as_float((unsigned)(e + 121) << 23);   // 2^(e-6)
        const float inv  = __uint_as_float((unsigned)(133 - e) << 23);   // 2^(6-e), exact

        #pragma unroll
        for (int j = 0; j < 8; ++j) {
            float q = rintf(x[j][k] * inv);            // round half to even (v_rndne_f32)
            q = fminf(fmaxf(q, -127.0f), 127.0f);
            x[j][k] = q * step;                        // exact pow2 scale
        }
    }

    #pragma unroll
    for (int j = 0; j < 8; ++j)
        __builtin_nontemporal_store(x[j], &out4[base + (size_t)j * HW4]);
}

extern "C" void kernel_launch(void* const* d_in, const int* in_sizes, int n_in,
                              void* d_out, int out_size, void* d_ws, size_t ws_size,
                              hipStream_t stream) {
    const v4f* in = (const v4f*)d_in[0];
    v4f* out = (v4f*)d_out;
    // per-n work: 32 channel-tiles * 784 float4 = 25088 threads = 98 blocks of 256
    dim3 grid(98, NBATCH);
    bfp_quant_kernel<<<grid, 256, 0, stream>>>(in, out);
}